// Round 3
// baseline (572.010 us; speedup 1.0000x reference)
//
#include <hip/hip_runtime.h>

// MQA: B=2, S=2048, D=2048, H=16, HD=128.  GEMMs bf16 MFMA 16x16x32, fp32 acc.
// Attention v3: S^T trick + small blocks for occupancy.
//   block = 2 waves (128 thr), wave owns 32 q-rows (qs=2), K-tile 64 keys.
//   grid 32x32 = 1024 blocks, LDS 32KB, launch_bounds(128,3) -> 3 waves/SIMD.

typedef unsigned short u16;
typedef __attribute__((ext_vector_type(8))) short bf16x8;   // 8 bf16 = 4 VGPR
typedef __attribute__((ext_vector_type(4))) short bf16x4;   // 4 bf16 = 2 VGPR
typedef __attribute__((ext_vector_type(4))) float f32x4;

#define D_MODEL 2048
#define SEQ     2048
#define NH      16
#define HD      128
#define BK      32

__device__ __forceinline__ u16 f2bf(float f){
  union { float f; unsigned u; } v; v.f = f;
  unsigned r = (v.u + 0x7FFFu + ((v.u >> 16) & 1u)) >> 16;  // RNE
  return (u16)r;
}

// pack two f32 -> one u32 holding 2 bf16 (lo = a, hi = b)
#if __has_builtin(__builtin_amdgcn_cvt_pk_bf16_f32)
__device__ __forceinline__ unsigned pack2bf(float a, float b){
  auto v = __builtin_amdgcn_cvt_pk_bf16_f32(a, b);
  unsigned u; __builtin_memcpy(&u, &v, 4); return u;
}
#else
__device__ __forceinline__ unsigned pack2bf(float a, float b){
  return (unsigned)f2bf(a) | ((unsigned)f2bf(b) << 16);
}
#endif

__device__ __forceinline__ void gll16(const void* g, void* l){
  __builtin_amdgcn_global_load_lds(
      (const __attribute__((address_space(1))) void*)g,
      (__attribute__((address_space(3))) void*)l, 16, 0, 0);
}

// ---------------- fp32 -> bf16 conversion of q,k,v ----------------
__global__ __launch_bounds__(256) void convert3_kernel(
    const float4* __restrict__ a, const float4* __restrict__ b, const float4* __restrict__ c,
    ushort4* __restrict__ oa, ushort4* __restrict__ ob, ushort4* __restrict__ oc){
  int i = blockIdx.x*256 + threadIdx.x;
  float4 va = a[i], vb = b[i], vc = c[i];
  ushort4 ra, rb, rc;
  ra.x=f2bf(va.x); ra.y=f2bf(va.y); ra.z=f2bf(va.z); ra.w=f2bf(va.w);
  rb.x=f2bf(vb.x); rb.y=f2bf(vb.y); rb.z=f2bf(vb.z); rb.w=f2bf(vb.w);
  rc.x=f2bf(vc.x); rc.y=f2bf(vc.y); rc.z=f2bf(vc.z); rc.w=f2bf(vc.w);
  oa[i]=ra; ob[i]=rb; oc[i]=rc;
}

// ---------------- transpose + convert: W[R][C] fp32 -> WT[C][R] bf16 ----------------
__global__ __launch_bounds__(256) void transpose_kernel(
    const float* __restrict__ in, u16* __restrict__ out, int R, int C){
  __shared__ float t[32][33];
  int c0 = blockIdx.x*32, r0 = blockIdx.y*32;
  int tx = threadIdx.x, ty = threadIdx.y;      // block (32,8)
  #pragma unroll
  for (int k=0;k<4;k++) t[ty+k*8][tx] = in[(size_t)(r0+ty+k*8)*C + c0+tx];
  __syncthreads();
  #pragma unroll
  for (int k=0;k<4;k++) out[(size_t)(c0+ty+k*8)*R + r0+tx] = f2bf(t[tx][ty+k*8]);
}

// ---------------- shared GEMM core (m97 structure) ----------------
__device__ __forceinline__ void gemm_core(
    const u16* __restrict__ A, const u16* __restrict__ BT,
    int lda, int ldb, int m0, int n0, int kbeg, int kend,
    u16* As, u16* Bs, f32x4 acc[4][4])
{
  const int t = threadIdx.x;
  const int w = t >> 6, l = t & 63;
  const int wr = w >> 1, wc = w & 1;
  const int c16 = l & 15, q = l >> 4;
  const int srow = l >> 2;
  const int sc   = ((l & 3) ^ ((l >> 3) & 3)) * 8;

  int aoff[4], boff[4];
  #pragma unroll
  for (int mt=0;mt<4;mt++){
    int row = wr*64 + mt*16 + c16;
    aoff[mt] = row*BK + ((q ^ ((row>>1)&3))*8);
  }
  #pragma unroll
  for (int nt=0;nt<4;nt++){
    int row = wc*64 + nt*16 + c16;
    boff[nt] = row*BK + ((q ^ ((row>>1)&3))*8);
  }

  for (int k0 = kbeg; k0 < kend; k0 += BK){
    #pragma unroll
    for (int half=0; half<2; half++){
      int r = half*64 + w*16 + srow;
      gll16(A  + (size_t)(m0+r)*lda + k0 + sc, As + (half*64 + w*16)*BK);
      gll16(BT + (size_t)(n0+r)*ldb + k0 + sc, Bs + (half*64 + w*16)*BK);
    }
    __syncthreads();
    bf16x8 af[4], bfr[4];
    #pragma unroll
    for (int mt=0;mt<4;mt++) af[mt]  = *(const bf16x8*)(As + aoff[mt]);
    #pragma unroll
    for (int nt=0;nt<4;nt++) bfr[nt] = *(const bf16x8*)(Bs + boff[nt]);
    #pragma unroll
    for (int mt=0;mt<4;mt++)
      #pragma unroll
      for (int nt=0;nt<4;nt++)
        acc[mt][nt] = __builtin_amdgcn_mfma_f32_16x16x32_bf16(af[mt], bfr[nt], acc[mt][nt], 0,0,0);
    __syncthreads();
  }
}

// ---------------- GEMM + bias, bf16 or fp32 output ----------------
template<bool BF16OUT>
__global__ __launch_bounds__(256) void gemm_bias(
    const u16* __restrict__ A, const u16* __restrict__ BT, const float* __restrict__ bias,
    void* __restrict__ C, int lda, int ldb, int ldc, int K)
{
  __shared__ u16 As[128*BK], Bs[128*BK];
  f32x4 acc[4][4];
  f32x4 z = {0.f,0.f,0.f,0.f};
  #pragma unroll
  for (int i=0;i<4;i++) for (int j=0;j<4;j++) acc[i][j] = z;
  int m0 = blockIdx.x*128, n0 = blockIdx.y*128;
  gemm_core(A, BT, lda, ldb, m0, n0, 0, K, As, Bs, acc);
  const int t = threadIdx.x, w = t>>6, l = t&63, wr = w>>1, wc = w&1, c16 = l&15, q = l>>4;
  #pragma unroll
  for (int mt=0;mt<4;mt++)
    #pragma unroll
    for (int nt=0;nt<4;nt++){
      int col = n0 + wc*64 + nt*16 + c16;
      float bv = bias[col];
      #pragma unroll
      for (int r=0;r<4;r++){
        int row = m0 + wr*64 + mt*16 + q*4 + r;
        float v = acc[mt][nt][r] + bv;
        if (BF16OUT) ((u16*)C)[(size_t)row*ldc + col] = f2bf(v);
        else         ((float*)C)[(size_t)row*ldc + col] = v;
      }
    }
}

// ---------------- fused K/V projection, split-K=4, fp32 partials ----------------
__global__ __launch_bounds__(256) void kvproj_kernel(
    const u16* __restrict__ kb, const u16* __restrict__ vb,
    const u16* __restrict__ WkT, const u16* __restrict__ WvT, float* __restrict__ part)
{
  __shared__ u16 As[128*BK], Bs[128*BK];
  f32x4 acc[4][4];
  f32x4 z = {0.f,0.f,0.f,0.f};
  #pragma unroll
  for (int i=0;i<4;i++) for (int j=0;j<4;j++) acc[i][j] = z;
  int m0 = blockIdx.x*128;
  int nb = blockIdx.y;
  int zi = blockIdx.z;
  const u16* A  = nb ? vb  : kb;
  const u16* BT = nb ? WvT : WkT;
  gemm_core(A, BT, D_MODEL, D_MODEL, m0, 0, zi*512, zi*512 + 512, As, Bs, acc);
  float* dst = part + (size_t)(zi*2 + nb)*524288;
  const int t = threadIdx.x, w = t>>6, l = t&63, wr = w>>1, wc = w&1, c16 = l&15, q = l>>4;
  #pragma unroll
  for (int mt=0;mt<4;mt++)
    #pragma unroll
    for (int nt=0;nt<4;nt++){
      int col = wc*64 + nt*16 + c16;
      #pragma unroll
      for (int r=0;r<4;r++){
        int row = m0 + wr*64 + mt*16 + q*4 + r;
        dst[(size_t)row*128 + col] = acc[mt][nt][r];
      }
    }
}

// ---------------- reduce split-K partials; Kp bf16 [4096][128], VpT bf16 [B][128][S] ----------------
__global__ __launch_bounds__(256) void kv_reduce_kernel(
    const float* __restrict__ part, const float* __restrict__ bk, const float* __restrict__ bv,
    u16* __restrict__ Kp, u16* __restrict__ VpT){
  int idx = blockIdx.x*256 + threadIdx.x;
  int d = idx & 127, sg = idx >> 7;
  float ka = 0.f, va = 0.f;
  #pragma unroll
  for (int zi=0; zi<4; zi++){
    ka += part[(size_t)(zi*2+0)*524288 + idx];
    va += part[(size_t)(zi*2+1)*524288 + idx];
  }
  Kp[idx] = f2bf(ka + bk[d]);
  int b = sg >> 11, sl = sg & 2047;
  VpT[(size_t)b*262144 + (size_t)d*2048 + sl] = f2bf(va + bv[d]);
}

// ---------------- flash attention v3 (S^T formulation, small blocks) ----------------
// block = 2 waves; wave owns 32 q-rows (2 sets of 16 q-cols); K-tile 64 keys.
// S^T = mfma(K,Q): lane q-col=c16, keys=quad*4+r -> softmax in-lane + 2 shuffles.
// P stays in registers as 16x16x16 PV B-operand; O^T accumulates in C-layout.
// LDS 32 KB: Ks[64key][128d] | Vs[128d][64k] (V^T), chunk8-XOR swizzled.
__global__ __launch_bounds__(128, 3) void attn_kernel(
    const u16* __restrict__ Qp, const u16* __restrict__ Kp,
    const u16* __restrict__ VpT, u16* __restrict__ attnb){
  __shared__ u16 lds[16384];
  u16* Ks = lds;            // 64 x 128 = 8192 u16
  u16* Vs = lds + 8192;     // 128 x 64 = 8192 u16
  const int t = threadIdx.x;
  const int w = t >> 6, l = t & 63;
  const int c16 = l & 15, q = l >> 4;

  const int qt = blockIdx.x;           // 0..31 (64 q-rows each)
  const int bh = blockIdx.y;           // 0..31
  const int b = bh >> 4, h = bh & 15;

  const u16* Qbase = Qp  + ((size_t)(b*SEQ + qt*64 + w*32))*D_MODEL + h*HD;
  const u16* Kbase = Kp  + (size_t)(b*SEQ)*HD;
  const u16* Vbase = VpT + (size_t)b*HD*SEQ;

  // stage this wave's 32 Q rows into scratch (Ks region), row swizzle key = r&15
  {
    u16* qtmp = lds + w*4096;
    #pragma unroll
    for (int j=0;j<8;j++){
      int r = j*4 + (l >> 4);
      int g = (l & 15) ^ (r & 15);
      gll16(Qbase + (size_t)r*D_MODEL + g*8, qtmp + j*512);
    }
  }
  __syncthreads();
  bf16x8 qf[2][4];
  #pragma unroll
  for (int qs=0;qs<2;qs++)
    #pragma unroll
    for (int kk=0;kk<4;kk++){
      int ch = kk*4 + q;
      qf[qs][kk] = *(const bf16x8*)(lds + w*4096 + (qs*16 + c16)*128 + ((ch ^ c16) & 15)*8);
    }
  __syncthreads();   // all waves done reading Q before K/V staging overwrites

  f32x4 o[2][8];
  f32x4 z4 = {0.f,0.f,0.f,0.f};
  #pragma unroll
  for (int qs=0;qs<2;qs++) for (int dt=0;dt<8;dt++) o[qs][dt] = z4;
  float mrow[2] = {-1e30f, -1e30f};
  float lrow[2] = {0.f, 0.f};
  const float cs = 0.08838834764831845f * 1.4426950408889634f;  // (1/sqrt(128))*log2(e)

  for (int kt = 0; kt < 32; kt++){
    // stage K tile (64key x 128d) and V^T tile (128d x 64k); 16 segs each, wave w: segs w*8..
    #pragma unroll
    for (int jj=0;jj<8;jj++){
      int seg = w*8 + jj;
      int r = seg*4 + (l >> 4);                 // key row 0..63
      int g = (l & 15) ^ (r & 15);
      gll16(Kbase + (size_t)(kt*64 + r)*HD + g*8, Ks + seg*512);
      int d = seg*8 + (l >> 3);                 // d row 0..127
      int gv = (l & 7) ^ (d & 7);
      gll16(Vbase + (size_t)d*SEQ + kt*64 + gv*8, Vs + seg*512);
    }
    __syncthreads();

    // S^T = K Q^T : lane q-col=c16, key rows quad*4+r (+16*kt16)
    f32x4 s[2][4];
    #pragma unroll
    for (int qs=0;qs<2;qs++) for (int kt16=0;kt16<4;kt16++) s[qs][kt16] = z4;
    #pragma unroll
    for (int kt16=0; kt16<4; kt16++){
      #pragma unroll
      for (int kk=0;kk<4;kk++){
        int ch = kk*4 + q;
        bf16x8 kf = *(const bf16x8*)(Ks + (kt16*16 + c16)*128 + ((ch ^ c16) & 15)*8);
        s[0][kt16] = __builtin_amdgcn_mfma_f32_16x16x32_bf16(kf, qf[0][kk], s[0][kt16], 0,0,0);
        s[1][kt16] = __builtin_amdgcn_mfma_f32_16x16x32_bf16(kf, qf[1][kk], s[1][kt16], 0,0,0);
      }
    }

    // online softmax: 16 in-lane values per q-set + 2 cross-quad shuffles
    float alpha[2];
    #pragma unroll
    for (int qs=0; qs<2; qs++){
      float vmax = s[qs][0][0];
      #pragma unroll
      for (int kt16=0;kt16<4;kt16++)
        #pragma unroll
        for (int r=0;r<4;r++) vmax = fmaxf(vmax, s[qs][kt16][r]);
      vmax = fmaxf(vmax, __shfl_xor(vmax, 16));
      vmax = fmaxf(vmax, __shfl_xor(vmax, 32));
      float mold = mrow[qs];
      float mnew = fmaxf(mold, vmax);
      float a = exp2f((mold - mnew)*cs);
      float mc = mnew*cs;
      float rsum = 0.f;
      #pragma unroll
      for (int kt16=0;kt16<4;kt16++)
        #pragma unroll
        for (int r=0;r<4;r++){
          float p = exp2f(__builtin_fmaf(s[qs][kt16][r], cs, -mc));
          s[qs][kt16][r] = p; rsum += p;
        }
      rsum += __shfl_xor(rsum, 16);
      rsum += __shfl_xor(rsum, 32);
      lrow[qs] = lrow[qs]*a + rsum;
      mrow[qs] = mnew;
      alpha[qs] = a;
    }
    // rescale O (skip when no lane's max moved — exact)
    unsigned long long allone = __ballot(alpha[0] == 1.f && alpha[1] == 1.f);
    if (allone != ~0ull){
      #pragma unroll
      for (int qs=0;qs<2;qs++)
        #pragma unroll
        for (int dt=0;dt<8;dt++)
          #pragma unroll
          for (int r=0;r<4;r++) o[qs][dt][r] *= alpha[qs];
    }

    // O^T += V^T P^T : A = V^T frag (LDS b64), B = P frag (registers)
    #pragma unroll
    for (int ks=0; ks<4; ks++){
      union { unsigned u[2]; bf16x4 v; } P0, P1;
      P0.u[0] = pack2bf(s[0][ks][0], s[0][ks][1]);
      P0.u[1] = pack2bf(s[0][ks][2], s[0][ks][3]);
      P1.u[0] = pack2bf(s[1][ks][0], s[1][ks][1]);
      P1.u[1] = pack2bf(s[1][ks][2], s[1][ks][3]);
      int c4 = ks*4 + q;
      #pragma unroll
      for (int dt=0; dt<8; dt++){
        int d = dt*16 + c16;
        int p8 = (c4 >> 1) ^ (d & 7);
        bf16x4 vf = *(const bf16x4*)(Vs + d*64 + p8*8 + (c4 & 1)*4);
        o[0][dt] = __builtin_amdgcn_mfma_f32_16x16x16bf16_1k(vf, P0.v, o[0][dt], 0,0,0);
        o[1][dt] = __builtin_amdgcn_mfma_f32_16x16x16bf16_1k(vf, P1.v, o[1][dt], 0,0,0);
      }
    }
    __syncthreads();
  }

  // normalize + write: lane holds O[q=c16+16qs][d=dt*16+quad*4+r] -> ushort4 along d
  #pragma unroll
  for (int qs=0;qs<2;qs++){
    float inv = 1.f / lrow[qs];
    int qrow = qt*64 + w*32 + qs*16 + c16;
    u16* dst = attnb + ((size_t)(b*SEQ) + qrow)*D_MODEL + h*HD + q*4;
    #pragma unroll
    for (int dt=0;dt<8;dt++){
      ushort4 pk;
      pk.x = f2bf(o[qs][dt][0]*inv);
      pk.y = f2bf(o[qs][dt][1]*inv);
      pk.z = f2bf(o[qs][dt][2]*inv);
      pk.w = f2bf(o[qs][dt][3]*inv);
      *(ushort4*)(dst + dt*16) = pk;
    }
  }
}

extern "C" void kernel_launch(void* const* d_in, const int* in_sizes, int n_in,
                              void* d_out, int out_size, void* d_ws, size_t ws_size,
                              hipStream_t stream) {
  (void)in_sizes; (void)n_in; (void)out_size; (void)ws_size;
  const float* query = (const float*)d_in[0];
  const float* key   = (const float*)d_in[1];
  const float* value = (const float*)d_in[2];
  const float* Wq    = (const float*)d_in[3];
  const float* bq    = (const float*)d_in[4];
  const float* Wk    = (const float*)d_in[5];
  const float* bk    = (const float*)d_in[6];
  const float* Wv    = (const float*)d_in[7];
  const float* bv    = (const float*)d_in[8];
  const float* Wo    = (const float*)d_in[9];
  const float* bo    = (const float*)d_in[10];
  float* out = (float*)d_out;

  char* W = (char*)d_ws;
  u16*  qb     = (u16*) (W + 0);          // 16 MB  bf16 query [4096][2048]
  u16*  kb     = (u16*) (W + 16777216);   // 16 MB  bf16 key
  u16*  vb     = (u16*) (W + 33554432);   // 16 MB  bf16 value
  u16*  WqT    = (u16*) (W + 50331648);   //  8 MB  Wq^T  [2048][2048]
  u16*  WoT    = (u16*) (W + 58720256);   //  8 MB  Wo^T
  u16*  WkT    = (u16*) (W + 67108864);   // .5 MB  Wk^T  [128][2048]
  u16*  WvT    = (u16*) (W + 67633152);   // .5 MB  Wv^T
  u16*  Qp     = (u16*) (W + 68157440);   // 16 MB  Q proj bf16 [4096][2048]
  u16*  Kp     = (u16*) (W + 84934656);   //  1 MB  K proj bf16 [4096][128]
  u16*  VpT    = (u16*) (W + 85983232);   //  1 MB  V proj^T bf16 [B][128][2048]
  u16*  attnb  = (u16*) (W + 87031808);   // 16 MB  attention out bf16 [4096][2048]
  float* kvpart= (float*)(W + 103809024); // 16 MB  split-K partials [4][2][4096][128]

  convert3_kernel<<<8192, 256, 0, stream>>>(
      (const float4*)query, (const float4*)key, (const float4*)value,
      (ushort4*)qb, (ushort4*)kb, (ushort4*)vb);
  transpose_kernel<<<dim3(64,64), dim3(32,8), 0, stream>>>(Wq, WqT, 2048, 2048);
  transpose_kernel<<<dim3(64,64), dim3(32,8), 0, stream>>>(Wo, WoT, 2048, 2048);
  transpose_kernel<<<dim3(4,64),  dim3(32,8), 0, stream>>>(Wk, WkT, 2048, 128);
  transpose_kernel<<<dim3(4,64),  dim3(32,8), 0, stream>>>(Wv, WvT, 2048, 128);

  gemm_bias<true><<<dim3(32,16), 256, 0, stream>>>(qb, WqT, bq, Qp, 2048, 2048, 2048, 2048);
  kvproj_kernel<<<dim3(32,2,4), 256, 0, stream>>>(kb, vb, WkT, WvT, kvpart);
  kv_reduce_kernel<<<2048, 256, 0, stream>>>(kvpart, bk, bv, Kp, VpT);
  attn_kernel<<<dim3(32,32), 128, 0, stream>>>(Qp, Kp, VpT, attnb);
  gemm_bias<false><<<dim3(32,16), 256, 0, stream>>>(attnb, WoT, bo, out, 2048, 2048, 2048, 2048);
}

// Round 4
// 525.154 us; speedup vs baseline: 1.0892x; 1.0892x over previous
//
#include <hip/hip_runtime.h>

// MQA: B=2, S=2048, D=2048, H=16, HD=128.  GEMMs bf16 MFMA 16x16x32, fp32 acc.
// Attention v4: round-2 S^T structure (4 waves, 128-key tiles) + register
// prefetch: next K/V tile is global_load'ed to VGPRs during compute of the
// current tile, ds_write'n to LDS after the barrier -> staging latency hidden.

typedef unsigned short u16;
typedef __attribute__((ext_vector_type(8))) short bf16x8;   // 8 bf16 = 4 VGPR
typedef __attribute__((ext_vector_type(4))) short bf16x4;   // 4 bf16 = 2 VGPR
typedef __attribute__((ext_vector_type(4))) float f32x4;

#define D_MODEL 2048
#define SEQ     2048
#define NH      16
#define HD      128
#define BK      32

__device__ __forceinline__ u16 f2bf(float f){
  union { float f; unsigned u; } v; v.f = f;
  unsigned r = (v.u + 0x7FFFu + ((v.u >> 16) & 1u)) >> 16;  // RNE
  return (u16)r;
}

// pack two f32 -> one u32 holding 2 bf16 (lo = a, hi = b)
#if __has_builtin(__builtin_amdgcn_cvt_pk_bf16_f32)
__device__ __forceinline__ unsigned pack2bf(float a, float b){
  auto v = __builtin_amdgcn_cvt_pk_bf16_f32(a, b);
  unsigned u; __builtin_memcpy(&u, &v, 4); return u;
}
#else
__device__ __forceinline__ unsigned pack2bf(float a, float b){
  return (unsigned)f2bf(a) | ((unsigned)f2bf(b) << 16);
}
#endif

__device__ __forceinline__ void gll16(const void* g, void* l){
  __builtin_amdgcn_global_load_lds(
      (const __attribute__((address_space(1))) void*)g,
      (__attribute__((address_space(3))) void*)l, 16, 0, 0);
}

// ---------------- fp32 -> bf16 conversion of q,k,v ----------------
__global__ __launch_bounds__(256) void convert3_kernel(
    const float4* __restrict__ a, const float4* __restrict__ b, const float4* __restrict__ c,
    ushort4* __restrict__ oa, ushort4* __restrict__ ob, ushort4* __restrict__ oc){
  int i = blockIdx.x*256 + threadIdx.x;
  float4 va = a[i], vb = b[i], vc = c[i];
  ushort4 ra, rb, rc;
  ra.x=f2bf(va.x); ra.y=f2bf(va.y); ra.z=f2bf(va.z); ra.w=f2bf(va.w);
  rb.x=f2bf(vb.x); rb.y=f2bf(vb.y); rb.z=f2bf(vb.z); rb.w=f2bf(vb.w);
  rc.x=f2bf(vc.x); rc.y=f2bf(vc.y); rc.z=f2bf(vc.z); rc.w=f2bf(vc.w);
  oa[i]=ra; ob[i]=rb; oc[i]=rc;
}

// ---------------- transpose + convert: W[R][C] fp32 -> WT[C][R] bf16 ----------------
__global__ __launch_bounds__(256) void transpose_kernel(
    const float* __restrict__ in, u16* __restrict__ out, int R, int C){
  __shared__ float t[32][33];
  int c0 = blockIdx.x*32, r0 = blockIdx.y*32;
  int tx = threadIdx.x, ty = threadIdx.y;      // block (32,8)
  #pragma unroll
  for (int k=0;k<4;k++) t[ty+k*8][tx] = in[(size_t)(r0+ty+k*8)*C + c0+tx];
  __syncthreads();
  #pragma unroll
  for (int k=0;k<4;k++) out[(size_t)(c0+ty+k*8)*R + r0+tx] = f2bf(t[tx][ty+k*8]);
}

// ---------------- shared GEMM core (m97 structure) ----------------
__device__ __forceinline__ void gemm_core(
    const u16* __restrict__ A, const u16* __restrict__ BT,
    int lda, int ldb, int m0, int n0, int kbeg, int kend,
    u16* As, u16* Bs, f32x4 acc[4][4])
{
  const int t = threadIdx.x;
  const int w = t >> 6, l = t & 63;
  const int wr = w >> 1, wc = w & 1;
  const int c16 = l & 15, q = l >> 4;
  const int srow = l >> 2;
  const int sc   = ((l & 3) ^ ((l >> 3) & 3)) * 8;

  int aoff[4], boff[4];
  #pragma unroll
  for (int mt=0;mt<4;mt++){
    int row = wr*64 + mt*16 + c16;
    aoff[mt] = row*BK + ((q ^ ((row>>1)&3))*8);
  }
  #pragma unroll
  for (int nt=0;nt<4;nt++){
    int row = wc*64 + nt*16 + c16;
    boff[nt] = row*BK + ((q ^ ((row>>1)&3))*8);
  }

  for (int k0 = kbeg; k0 < kend; k0 += BK){
    #pragma unroll
    for (int half=0; half<2; half++){
      int r = half*64 + w*16 + srow;
      gll16(A  + (size_t)(m0+r)*lda + k0 + sc, As + (half*64 + w*16)*BK);
      gll16(BT + (size_t)(n0+r)*ldb + k0 + sc, Bs + (half*64 + w*16)*BK);
    }
    __syncthreads();
    bf16x8 af[4], bfr[4];
    #pragma unroll
    for (int mt=0;mt<4;mt++) af[mt]  = *(const bf16x8*)(As + aoff[mt]);
    #pragma unroll
    for (int nt=0;nt<4;nt++) bfr[nt] = *(const bf16x8*)(Bs + boff[nt]);
    #pragma unroll
    for (int mt=0;mt<4;mt++)
      #pragma unroll
      for (int nt=0;nt<4;nt++)
        acc[mt][nt] = __builtin_amdgcn_mfma_f32_16x16x32_bf16(af[mt], bfr[nt], acc[mt][nt], 0,0,0);
    __syncthreads();
  }
}

// ---------------- GEMM + bias, bf16 or fp32 output ----------------
template<bool BF16OUT>
__global__ __launch_bounds__(256) void gemm_bias(
    const u16* __restrict__ A, const u16* __restrict__ BT, const float* __restrict__ bias,
    void* __restrict__ C, int lda, int ldb, int ldc, int K)
{
  __shared__ u16 As[128*BK], Bs[128*BK];
  f32x4 acc[4][4];
  f32x4 z = {0.f,0.f,0.f,0.f};
  #pragma unroll
  for (int i=0;i<4;i++) for (int j=0;j<4;j++) acc[i][j] = z;
  int m0 = blockIdx.x*128, n0 = blockIdx.y*128;
  gemm_core(A, BT, lda, ldb, m0, n0, 0, K, As, Bs, acc);
  const int t = threadIdx.x, w = t>>6, l = t&63, wr = w>>1, wc = w&1, c16 = l&15, q = l>>4;
  #pragma unroll
  for (int mt=0;mt<4;mt++)
    #pragma unroll
    for (int nt=0;nt<4;nt++){
      int col = n0 + wc*64 + nt*16 + c16;
      float bv = bias[col];
      #pragma unroll
      for (int r=0;r<4;r++){
        int row = m0 + wr*64 + mt*16 + q*4 + r;
        float v = acc[mt][nt][r] + bv;
        if (BF16OUT) ((u16*)C)[(size_t)row*ldc + col] = f2bf(v);
        else         ((float*)C)[(size_t)row*ldc + col] = v;
      }
    }
}

// ---------------- fused K/V projection, split-K=4, fp32 partials ----------------
__global__ __launch_bounds__(256) void kvproj_kernel(
    const u16* __restrict__ kb, const u16* __restrict__ vb,
    const u16* __restrict__ WkT, const u16* __restrict__ WvT, float* __restrict__ part)
{
  __shared__ u16 As[128*BK], Bs[128*BK];
  f32x4 acc[4][4];
  f32x4 z = {0.f,0.f,0.f,0.f};
  #pragma unroll
  for (int i=0;i<4;i++) for (int j=0;j<4;j++) acc[i][j] = z;
  int m0 = blockIdx.x*128;
  int nb = blockIdx.y;
  int zi = blockIdx.z;
  const u16* A  = nb ? vb  : kb;
  const u16* BT = nb ? WvT : WkT;
  gemm_core(A, BT, D_MODEL, D_MODEL, m0, 0, zi*512, zi*512 + 512, As, Bs, acc);
  float* dst = part + (size_t)(zi*2 + nb)*524288;
  const int t = threadIdx.x, w = t>>6, l = t&63, wr = w>>1, wc = w&1, c16 = l&15, q = l>>4;
  #pragma unroll
  for (int mt=0;mt<4;mt++)
    #pragma unroll
    for (int nt=0;nt<4;nt++){
      int col = wc*64 + nt*16 + c16;
      #pragma unroll
      for (int r=0;r<4;r++){
        int row = m0 + wr*64 + mt*16 + q*4 + r;
        dst[(size_t)row*128 + col] = acc[mt][nt][r];
      }
    }
}

// ---------------- reduce split-K partials; Kp bf16 [4096][128], VpT bf16 [B][128][S] ----------------
__global__ __launch_bounds__(256) void kv_reduce_kernel(
    const float* __restrict__ part, const float* __restrict__ bk, const float* __restrict__ bv,
    u16* __restrict__ Kp, u16* __restrict__ VpT){
  int idx = blockIdx.x*256 + threadIdx.x;
  int d = idx & 127, sg = idx >> 7;
  float ka = 0.f, va = 0.f;
  #pragma unroll
  for (int zi=0; zi<4; zi++){
    ka += part[(size_t)(zi*2+0)*524288 + idx];
    va += part[(size_t)(zi*2+1)*524288 + idx];
  }
  Kp[idx] = f2bf(ka + bk[d]);
  int b = sg >> 11, sl = sg & 2047;
  VpT[(size_t)b*262144 + (size_t)d*2048 + sl] = f2bf(va + bv[d]);
}

// ---------------- flash attention v4 (S^T + register-prefetch pipeline) ----------------
// block = 4 waves; wave owns 32 q-rows (2 x 16 q-cols); K-tile 128 keys, 16 iters.
// Prefetch next K (iter start) and next V (after softmax) into VGPRs; compute
// from LDS; barrier; ds_write prefetched tile; barrier. Latency hidden.
// LDS 64 KB: Ks[128key][128d] | Vs[128d][128k], chunk8-XOR swizzled.
__global__ __launch_bounds__(256, 2) void attn_kernel(
    const u16* __restrict__ Qp, const u16* __restrict__ Kp,
    const u16* __restrict__ VpT, u16* __restrict__ attnb){
  __shared__ u16 lds[32768];
  u16* Ks = lds;            // 128 x 128
  u16* Vs = lds + 16384;    // 128 x 128 (V^T)
  const int t = threadIdx.x;
  const int w = t >> 6, l = t & 63;
  const int c16 = l & 15, q = l >> 4;

  const int qt = blockIdx.x;           // 0..15
  const int bh = blockIdx.y;           // 0..31
  const int b = bh >> 4, h = bh & 15;

  const u16* Qbase = Qp  + ((size_t)(b*SEQ + qt*128 + w*32))*D_MODEL + h*HD;
  const u16* Kbase = Kp  + (size_t)(b*SEQ)*HD;
  const u16* Vbase = VpT + (size_t)b*HD*SEQ;

  // staging geometry (same for K and V, and for the reg-prefetch writes):
  // seg j (0..7): rows j*16 + w*4 + (l>>4), chunk position l&15 holds
  // global chunk (l&15)^(row&15). LDS addr = j*2048 + w*512 + l*8.
  const int srow = w*4 + (l >> 4);          // row within 16-row seg
  const int ldso = w*512 + l*8;             // per-thread LDS offset within seg

  uint4 kpre[8], vpre[8];

  // ---- prologue: stage Q (gll), prefetch tile 0 to regs ----
  {
    u16* qtmp = lds + w*4096;
    #pragma unroll
    for (int j=0;j<8;j++){
      int r = j*4 + (l >> 4);
      int g = (l & 15) ^ (r & 15);
      gll16(Qbase + (size_t)r*D_MODEL + g*8, qtmp + j*512);
    }
  }
  #pragma unroll
  for (int j=0;j<8;j++){
    int r = j*16 + srow;
    int g = (l & 15) ^ (r & 15);
    kpre[j] = *(const uint4*)(Kbase + (size_t)r*HD + g*8);
    vpre[j] = *(const uint4*)(Vbase + (size_t)r*SEQ + g*8);
  }
  __syncthreads();
  bf16x8 qf[2][4];
  #pragma unroll
  for (int qs=0;qs<2;qs++)
    #pragma unroll
    for (int kk=0;kk<4;kk++){
      int ch = kk*4 + q;
      qf[qs][kk] = *(const bf16x8*)(lds + w*4096 + (qs*16 + c16)*128 + ((ch ^ c16) & 15)*8);
    }
  __syncthreads();   // all waves done reading Q scratch
  #pragma unroll
  for (int j=0;j<8;j++){
    *(uint4*)(Ks + j*2048 + ldso) = kpre[j];
    *(uint4*)(Vs + j*2048 + ldso) = vpre[j];
  }
  __syncthreads();   // tile 0 visible

  f32x4 o[2][8];
  f32x4 z4 = {0.f,0.f,0.f,0.f};
  #pragma unroll
  for (int qs=0;qs<2;qs++) for (int dt=0;dt<8;dt++) o[qs][dt] = z4;
  float mrow[2] = {-1e30f, -1e30f};
  float lrow[2] = {0.f, 0.f};
  const float cs = 0.08838834764831845f * 1.4426950408889634f;  // (1/sqrt(128))*log2(e)

  for (int kt = 0; kt < 16; kt++){
    // prefetch next K tile to regs (overlaps QK+softmax+PV)
    if (kt < 15){
      #pragma unroll
      for (int j=0;j<8;j++){
        int r = j*16 + srow;
        int g = (l & 15) ^ (r & 15);
        kpre[j] = *(const uint4*)(Kbase + (size_t)((kt+1)*128 + r)*HD + g*8);
      }
    }

    // S^T = K Q^T : lane q-col=c16, key rows quad*4+r (+16*kt8)
    f32x4 s[2][8];
    #pragma unroll
    for (int qs=0;qs<2;qs++) for (int kt8=0;kt8<8;kt8++) s[qs][kt8] = z4;
    #pragma unroll
    for (int kt8=0; kt8<8; kt8++){
      #pragma unroll
      for (int kk=0;kk<4;kk++){
        int ch = kk*4 + q;
        bf16x8 kf = *(const bf16x8*)(Ks + (kt8*16 + c16)*128 + ((ch ^ c16) & 15)*8);
        s[0][kt8] = __builtin_amdgcn_mfma_f32_16x16x32_bf16(kf, qf[0][kk], s[0][kt8], 0,0,0);
        s[1][kt8] = __builtin_amdgcn_mfma_f32_16x16x32_bf16(kf, qf[1][kk], s[1][kt8], 0,0,0);
      }
    }

    // online softmax: 32 in-lane values per q-set + 2 cross-quad shuffles
    float alpha[2];
    #pragma unroll
    for (int qs=0; qs<2; qs++){
      float vmax = s[qs][0][0];
      #pragma unroll
      for (int kt8=0;kt8<8;kt8++)
        #pragma unroll
        for (int r=0;r<4;r++) vmax = fmaxf(vmax, s[qs][kt8][r]);
      vmax = fmaxf(vmax, __shfl_xor(vmax, 16));
      vmax = fmaxf(vmax, __shfl_xor(vmax, 32));
      float mold = mrow[qs];
      float mnew = fmaxf(mold, vmax);
      float a = exp2f((mold - mnew)*cs);
      float mc = mnew*cs;
      float rsum = 0.f;
      #pragma unroll
      for (int kt8=0;kt8<8;kt8++)
        #pragma unroll
        for (int r=0;r<4;r++){
          float p = exp2f(__builtin_fmaf(s[qs][kt8][r], cs, -mc));
          s[qs][kt8][r] = p; rsum += p;
        }
      rsum += __shfl_xor(rsum, 16);
      rsum += __shfl_xor(rsum, 32);
      lrow[qs] = lrow[qs]*a + rsum;
      mrow[qs] = mnew;
      alpha[qs] = a;
    }
    // rescale O (skip when no lane's max moved — exact)
    unsigned long long allone = __ballot(alpha[0] == 1.f && alpha[1] == 1.f);
    if (allone != ~0ull){
      #pragma unroll
      for (int qs=0;qs<2;qs++)
        #pragma unroll
        for (int dt=0;dt<8;dt++)
          #pragma unroll
          for (int r=0;r<4;r++) o[qs][dt][r] *= alpha[qs];
    }

    // pack P to bf16 registers (frees s[])
    union { unsigned u[2]; bf16x4 v; } P[2][8];
    #pragma unroll
    for (int kt8=0;kt8<8;kt8++){
      P[0][kt8].u[0] = pack2bf(s[0][kt8][0], s[0][kt8][1]);
      P[0][kt8].u[1] = pack2bf(s[0][kt8][2], s[0][kt8][3]);
      P[1][kt8].u[0] = pack2bf(s[1][kt8][0], s[1][kt8][1]);
      P[1][kt8].u[1] = pack2bf(s[1][kt8][2], s[1][kt8][3]);
    }

    // prefetch next V tile to regs (overlaps PV)
    if (kt < 15){
      #pragma unroll
      for (int j=0;j<8;j++){
        int r = j*16 + srow;
        int g = (l & 15) ^ (r & 15);
        vpre[j] = *(const uint4*)(Vbase + (size_t)r*SEQ + (kt+1)*128 + g*8);
      }
    }

    // O^T += V^T P^T : A = V^T frag (LDS b64), B = P frag (registers)
    #pragma unroll
    for (int kt8=0; kt8<8; kt8++){
      int c4 = kt8*4 + q;
      #pragma unroll
      for (int dt=0; dt<8; dt++){
        int d = dt*16 + c16;
        int p8 = (c4 >> 1) ^ (d & 15);
        bf16x4 vf = *(const bf16x4*)(Vs + d*128 + p8*8 + (c4 & 1)*4);
        o[0][dt] = __builtin_amdgcn_mfma_f32_16x16x16bf16_1k(vf, P[0][kt8].v, o[0][dt], 0,0,0);
        o[1][dt] = __builtin_amdgcn_mfma_f32_16x16x16bf16_1k(vf, P[1][kt8].v, o[1][dt], 0,0,0);
      }
    }
    __syncthreads();   // all waves done reading tile kt (also drains prefetch vmcnt)
    if (kt < 15){
      #pragma unroll
      for (int j=0;j<8;j++){
        *(uint4*)(Ks + j*2048 + ldso) = kpre[j];
        *(uint4*)(Vs + j*2048 + ldso) = vpre[j];
      }
      __syncthreads(); // tile kt+1 visible
    }
  }

  // normalize + write: lane holds O[q=c16+16qs][d=dt*16+quad*4+r] -> ushort4 along d
  #pragma unroll
  for (int qs=0;qs<2;qs++){
    float inv = 1.f / lrow[qs];
    int qrow = qt*128 + w*32 + qs*16 + c16;
    u16* dst = attnb + ((size_t)(b*SEQ) + qrow)*D_MODEL + h*HD + q*4;
    #pragma unroll
    for (int dt=0;dt<8;dt++){
      ushort4 pk;
      pk.x = f2bf(o[qs][dt][0]*inv);
      pk.y = f2bf(o[qs][dt][1]*inv);
      pk.z = f2bf(o[qs][dt][2]*inv);
      pk.w = f2bf(o[qs][dt][3]*inv);
      *(ushort4*)(dst + dt*16) = pk;
    }
  }
}

extern "C" void kernel_launch(void* const* d_in, const int* in_sizes, int n_in,
                              void* d_out, int out_size, void* d_ws, size_t ws_size,
                              hipStream_t stream) {
  (void)in_sizes; (void)n_in; (void)out_size; (void)ws_size;
  const float* query = (const float*)d_in[0];
  const float* key   = (const float*)d_in[1];
  const float* value = (const float*)d_in[2];
  const float* Wq    = (const float*)d_in[3];
  const float* bq    = (const float*)d_in[4];
  const float* Wk    = (const float*)d_in[5];
  const float* bk    = (const float*)d_in[6];
  const float* Wv    = (const float*)d_in[7];
  const float* bv    = (const float*)d_in[8];
  const float* Wo    = (const float*)d_in[9];
  const float* bo    = (const float*)d_in[10];
  float* out = (float*)d_out;

  char* W = (char*)d_ws;
  u16*  qb     = (u16*) (W + 0);          // 16 MB  bf16 query [4096][2048]
  u16*  kb     = (u16*) (W + 16777216);   // 16 MB  bf16 key
  u16*  vb     = (u16*) (W + 33554432);   // 16 MB  bf16 value
  u16*  WqT    = (u16*) (W + 50331648);   //  8 MB  Wq^T  [2048][2048]
  u16*  WoT    = (u16*) (W + 58720256);   //  8 MB  Wo^T
  u16*  WkT    = (u16*) (W + 67108864);   // .5 MB  Wk^T  [128][2048]
  u16*  WvT    = (u16*) (W + 67633152);   // .5 MB  Wv^T
  u16*  Qp     = (u16*) (W + 68157440);   // 16 MB  Q proj bf16 [4096][2048]
  u16*  Kp     = (u16*) (W + 84934656);   //  1 MB  K proj bf16 [4096][128]
  u16*  VpT    = (u16*) (W + 85983232);   //  1 MB  V proj^T bf16 [B][128][2048]
  u16*  attnb  = (u16*) (W + 87031808);   // 16 MB  attention out bf16 [4096][2048]
  float* kvpart= (float*)(W + 103809024); // 16 MB  split-K partials [4][2][4096][128]

  convert3_kernel<<<8192, 256, 0, stream>>>(
      (const float4*)query, (const float4*)key, (const float4*)value,
      (ushort4*)qb, (ushort4*)kb, (ushort4*)vb);
  transpose_kernel<<<dim3(64,64), dim3(32,8), 0, stream>>>(Wq, WqT, 2048, 2048);
  transpose_kernel<<<dim3(64,64), dim3(32,8), 0, stream>>>(Wo, WoT, 2048, 2048);
  transpose_kernel<<<dim3(4,64),  dim3(32,8), 0, stream>>>(Wk, WkT, 2048, 128);
  transpose_kernel<<<dim3(4,64),  dim3(32,8), 0, stream>>>(Wv, WvT, 2048, 128);

  gemm_bias<true><<<dim3(32,16), 256, 0, stream>>>(qb, WqT, bq, Qp, 2048, 2048, 2048, 2048);
  kvproj_kernel<<<dim3(32,2,4), 256, 0, stream>>>(kb, vb, WkT, WvT, kvpart);
  kv_reduce_kernel<<<2048, 256, 0, stream>>>(kvpart, bk, bv, Kp, VpT);
  attn_kernel<<<dim3(16,32), 256, 0, stream>>>(Qp, Kp, VpT, attnb);
  gemm_bias<false><<<dim3(32,16), 256, 0, stream>>>(attnb, WoT, bo, out, 2048, 2048, 2048, 2048);
}

// Round 5
// 424.176 us; speedup vs baseline: 1.3485x; 1.2381x over previous
//
#include <hip/hip_runtime.h>

// MQA: B=2, S=2048, D=2048, H=16, HD=128.  GEMMs bf16 MFMA 16x16x32, fp32 acc.
// v5: attention = round-2 S^T structure with staggered gll issue (V at iter
// top overlapping QK+softmax; next-K after mid-barrier overlapping PV).
// GEMM core double-buffered (1 barrier/iter, gll for tile i+1 issued at top
// of iter i). Q-proj + KV-proj fused into one launch; 4 transposes fused.

typedef unsigned short u16;
typedef __attribute__((ext_vector_type(8))) short bf16x8;   // 8 bf16 = 4 VGPR
typedef __attribute__((ext_vector_type(4))) short bf16x4;   // 4 bf16 = 2 VGPR
typedef __attribute__((ext_vector_type(4))) float f32x4;

#define D_MODEL 2048
#define SEQ     2048
#define NH      16
#define HD      128
#define BK      32

__device__ __forceinline__ u16 f2bf(float f){
  union { float f; unsigned u; } v; v.f = f;
  unsigned r = (v.u + 0x7FFFu + ((v.u >> 16) & 1u)) >> 16;  // RNE
  return (u16)r;
}

#if __has_builtin(__builtin_amdgcn_cvt_pk_bf16_f32)
__device__ __forceinline__ unsigned pack2bf(float a, float b){
  auto v = __builtin_amdgcn_cvt_pk_bf16_f32(a, b);
  unsigned u; __builtin_memcpy(&u, &v, 4); return u;
}
#else
__device__ __forceinline__ unsigned pack2bf(float a, float b){
  return (unsigned)f2bf(a) | ((unsigned)f2bf(b) << 16);
}
#endif

__device__ __forceinline__ void gll16(const void* g, void* l){
  __builtin_amdgcn_global_load_lds(
      (const __attribute__((address_space(1))) void*)g,
      (__attribute__((address_space(3))) void*)l, 16, 0, 0);
}

// ---------------- fp32 -> bf16 conversion of q,k,v ----------------
__global__ __launch_bounds__(256) void convert3_kernel(
    const float4* __restrict__ a, const float4* __restrict__ b, const float4* __restrict__ c,
    ushort4* __restrict__ oa, ushort4* __restrict__ ob, ushort4* __restrict__ oc){
  int i = blockIdx.x*256 + threadIdx.x;
  float4 va = a[i], vb = b[i], vc = c[i];
  ushort4 ra, rb, rc;
  ra.x=f2bf(va.x); ra.y=f2bf(va.y); ra.z=f2bf(va.z); ra.w=f2bf(va.w);
  rb.x=f2bf(vb.x); rb.y=f2bf(vb.y); rb.z=f2bf(vb.z); rb.w=f2bf(vb.w);
  rc.x=f2bf(vc.x); rc.y=f2bf(vc.y); rc.z=f2bf(vc.z); rc.w=f2bf(vc.w);
  oa[i]=ra; ob[i]=rb; oc[i]=rc;
}

// ---------------- all 4 weight transposes in one launch ----------------
__global__ __launch_bounds__(256) void transpose_all(
    const float* __restrict__ Wq, const float* __restrict__ Wo,
    const float* __restrict__ Wk, const float* __restrict__ Wv,
    u16* __restrict__ WqT, u16* __restrict__ WoT,
    u16* __restrict__ WkT, u16* __restrict__ WvT){
  __shared__ float tt[32][33];
  int id = blockIdx.x;
  const float* in; u16* outp; int C, bx, by;
  if (id < 4096)      { in=Wq; outp=WqT; C=2048; bx=id&63;        by=id>>6; }
  else if (id < 8192) { id-=4096; in=Wo; outp=WoT; C=2048; bx=id&63; by=id>>6; }
  else if (id < 8448) { id-=8192; in=Wk; outp=WkT; C=128;  bx=id&3;  by=id>>2; }
  else                { id-=8448; in=Wv; outp=WvT; C=128;  bx=id&3;  by=id>>2; }
  const int R = 2048;
  int c0 = bx*32, r0 = by*32;
  int tx = threadIdx.x & 31, ty = threadIdx.x >> 5;   // (32,8) flattened
  #pragma unroll
  for (int k=0;k<4;k++) tt[ty+k*8][tx] = in[(size_t)(r0+ty+k*8)*C + c0+tx];
  __syncthreads();
  #pragma unroll
  for (int k=0;k<4;k++) outp[(size_t)(c0+ty+k*8)*R + r0+tx] = f2bf(tt[tx][ty+k*8]);
}

// ---------------- double-buffered GEMM core: 1 barrier/iter ----------------
// gll for tile i+1 issued at top of iter i (after the barrier that freed the
// target buffer); drained by the next iter's barrier AFTER this iter's MFMAs.
__device__ __forceinline__ void gemm_core_db(
    const u16* __restrict__ A, const u16* __restrict__ BT,
    int lda, int ldb, int m0, int n0, int kbeg, int kend,
    u16* As, u16* Bs, f32x4 acc[4][4])
{
  const int t = threadIdx.x;
  const int w = t >> 6, l = t & 63;
  const int wr = w >> 1, wc = w & 1;
  const int c16 = l & 15, q = l >> 4;
  const int srow = l >> 2;
  const int sc   = ((l & 3) ^ ((l >> 3) & 3)) * 8;

  int aoff[4], boff[4];
  #pragma unroll
  for (int mt=0;mt<4;mt++){
    int row = wr*64 + mt*16 + c16;
    aoff[mt] = row*BK + ((q ^ ((row>>1)&3))*8);
  }
  #pragma unroll
  for (int nt=0;nt<4;nt++){
    int row = wc*64 + nt*16 + c16;
    boff[nt] = row*BK + ((q ^ ((row>>1)&3))*8);
  }

  auto issue = [&](int k0, int buf){
    u16* Ad = As + buf*4096;
    u16* Bd = Bs + buf*4096;
    #pragma unroll
    for (int half=0; half<2; half++){
      int r = half*64 + w*16 + srow;
      gll16(A  + (size_t)(m0+r)*lda + k0 + sc, Ad + (half*64 + w*16)*BK);
      gll16(BT + (size_t)(n0+r)*ldb + k0 + sc, Bd + (half*64 + w*16)*BK);
    }
  };

  const int n = (kend - kbeg) / BK;
  issue(kbeg, 0);
  for (int i = 0; i < n; i++){
    __syncthreads();                       // tile i arrived; buf (i+1)&1 free
    if (i+1 < n) issue(kbeg + (i+1)*BK, (i+1)&1);
    const u16* Ab = As + (i&1)*4096;
    const u16* Bb = Bs + (i&1)*4096;
    bf16x8 af[4], bfr[4];
    #pragma unroll
    for (int mt=0;mt<4;mt++) af[mt]  = *(const bf16x8*)(Ab + aoff[mt]);
    #pragma unroll
    for (int nt=0;nt<4;nt++) bfr[nt] = *(const bf16x8*)(Bb + boff[nt]);
    #pragma unroll
    for (int mt=0;mt<4;mt++)
      #pragma unroll
      for (int nt=0;nt<4;nt++)
        acc[mt][nt] = __builtin_amdgcn_mfma_f32_16x16x32_bf16(af[mt], bfr[nt], acc[mt][nt], 0,0,0);
  }
}

// ---------------- fused Q-projection + K/V projection ----------------
// blocks 0..511: Q-proj (M=4096, N=2048, K=2048), bf16 out + bias.
// blocks 512..767: K/V proj split-K=4, fp32 partials.
__global__ __launch_bounds__(256) void proj_kernel(
    const u16* __restrict__ qb, const u16* __restrict__ kb, const u16* __restrict__ vb,
    const u16* __restrict__ WqT, const u16* __restrict__ WkT, const u16* __restrict__ WvT,
    const float* __restrict__ bq, u16* __restrict__ Qp, float* __restrict__ part)
{
  __shared__ u16 As[2*4096], Bs[2*4096];
  f32x4 acc[4][4];
  f32x4 z = {0.f,0.f,0.f,0.f};
  #pragma unroll
  for (int i=0;i<4;i++) for (int j=0;j<4;j++) acc[i][j] = z;
  const int t = threadIdx.x, w = t>>6, l = t&63, wr = w>>1, wc = w&1, c16 = l&15, q = l>>4;
  int id = blockIdx.x;
  if (id < 512){
    int m0 = (id & 31)*128, n0 = (id >> 5)*128;
    gemm_core_db(qb, WqT, 2048, 2048, m0, n0, 0, 2048, As, Bs, acc);
    #pragma unroll
    for (int mt=0;mt<4;mt++)
      #pragma unroll
      for (int nt=0;nt<4;nt++){
        int col = n0 + wc*64 + nt*16 + c16;
        float bv = bq[col];
        #pragma unroll
        for (int r=0;r<4;r++){
          int row = m0 + wr*64 + mt*16 + q*4 + r;
          Qp[(size_t)row*D_MODEL + col] = f2bf(acc[mt][nt][r] + bv);
        }
      }
  } else {
    int kvid = id - 512;
    int zi = kvid & 3, nb = (kvid >> 2) & 1, mi = kvid >> 3;
    const u16* Am = nb ? vb  : kb;
    const u16* Bm = nb ? WvT : WkT;
    gemm_core_db(Am, Bm, 2048, 2048, mi*128, 0, zi*512, zi*512+512, As, Bs, acc);
    float* dst = part + (size_t)(zi*2 + nb)*524288;   // [z][nb][4096][128]
    #pragma unroll
    for (int mt=0;mt<4;mt++)
      #pragma unroll
      for (int nt=0;nt<4;nt++){
        int col = wc*64 + nt*16 + c16;
        #pragma unroll
        for (int r=0;r<4;r++){
          int row = mi*128 + wr*64 + mt*16 + q*4 + r;
          dst[(size_t)row*128 + col] = acc[mt][nt][r];
        }
      }
  }
}

// ---------------- O-projection GEMM + bias, fp32 out ----------------
__global__ __launch_bounds__(256) void oproj_kernel(
    const u16* __restrict__ A, const u16* __restrict__ BT, const float* __restrict__ bias,
    float* __restrict__ C)
{
  __shared__ u16 As[2*4096], Bs[2*4096];
  f32x4 acc[4][4];
  f32x4 z = {0.f,0.f,0.f,0.f};
  #pragma unroll
  for (int i=0;i<4;i++) for (int j=0;j<4;j++) acc[i][j] = z;
  int m0 = blockIdx.x*128, n0 = blockIdx.y*128;
  gemm_core_db(A, BT, 2048, 2048, m0, n0, 0, 2048, As, Bs, acc);
  const int t = threadIdx.x, w = t>>6, l = t&63, wr = w>>1, wc = w&1, c16 = l&15, q = l>>4;
  #pragma unroll
  for (int mt=0;mt<4;mt++)
    #pragma unroll
    for (int nt=0;nt<4;nt++){
      int col = n0 + wc*64 + nt*16 + c16;
      float bv = bias[col];
      #pragma unroll
      for (int r=0;r<4;r++){
        int row = m0 + wr*64 + mt*16 + q*4 + r;
        C[(size_t)row*D_MODEL + col] = acc[mt][nt][r] + bv;
      }
    }
}

// ---------------- reduce split-K partials; Kp bf16 [4096][128], VpT bf16 [B][128][S] ----------------
__global__ __launch_bounds__(256) void kv_reduce_kernel(
    const float* __restrict__ part, const float* __restrict__ bk, const float* __restrict__ bv,
    u16* __restrict__ Kp, u16* __restrict__ VpT){
  int idx = blockIdx.x*256 + threadIdx.x;
  int d = idx & 127, sg = idx >> 7;
  float ka = 0.f, va = 0.f;
  #pragma unroll
  for (int zi=0; zi<4; zi++){
    ka += part[(size_t)(zi*2+0)*524288 + idx];
    va += part[(size_t)(zi*2+1)*524288 + idx];
  }
  Kp[idx] = f2bf(ka + bk[d]);
  int b = sg >> 11, sl = sg & 2047;
  VpT[(size_t)b*262144 + (size_t)d*2048 + sl] = f2bf(va + bv[d]);
}

// ---------------- flash attention v5 (S^T + staggered gll issue) ----------------
// block = 4 waves; wave owns 32 q-rows (2 x 16 q-cols); K-tile 128 keys, 16 iters.
// V_kt gll issued at iter top (drained by mid-barrier after QK+softmax);
// K_{kt+1} gll issued after mid-barrier (drained by end-barrier after PV).
// LDS 64 KB: Ks[128key][128d] | Vs[128d][128k], chunk8-XOR swizzled.
__global__ __launch_bounds__(256, 2) void attn_kernel(
    const u16* __restrict__ Qp, const u16* __restrict__ Kp,
    const u16* __restrict__ VpT, u16* __restrict__ attnb){
  __shared__ u16 lds[32768];
  u16* Ks = lds;            // 128 x 128
  u16* Vs = lds + 16384;    // 128 x 128 (V^T)
  const int t = threadIdx.x;
  const int w = t >> 6, l = t & 63;
  const int c16 = l & 15, q = l >> 4;

  const int qt = blockIdx.x;           // 0..15
  const int bh = blockIdx.y;           // 0..31
  const int b = bh >> 4, h = bh & 15;

  const u16* Qbase = Qp  + ((size_t)(b*SEQ + qt*128 + w*32))*D_MODEL + h*HD;
  const u16* Kbase = Kp  + (size_t)(b*SEQ)*HD;
  const u16* Vbase = VpT + (size_t)b*HD*SEQ;

  // ---- prologue: stage Q into Vs region + K tile 0 into Ks, concurrently ----
  {
    u16* qtmp = lds + 16384 + w*4096;
    #pragma unroll
    for (int j=0;j<8;j++){
      int r = j*4 + (l >> 4);
      int g = (l & 15) ^ (r & 15);
      gll16(Qbase + (size_t)r*D_MODEL + g*8, qtmp + j*512);
    }
  }
  #pragma unroll
  for (int j=0;j<8;j++){
    int r = j*16 + w*4 + (l >> 4);
    int g = (l & 15) ^ (r & 15);
    gll16(Kbase + (size_t)r*HD + g*8, Ks + j*2048 + w*512);
  }
  __syncthreads();   // Q + K0 arrived
  bf16x8 qf[2][4];
  #pragma unroll
  for (int qs=0;qs<2;qs++)
    #pragma unroll
    for (int kk=0;kk<4;kk++){
      int ch = kk*4 + q;
      qf[qs][kk] = *(const bf16x8*)(lds + 16384 + w*4096 + (qs*16 + c16)*128 + ((ch ^ c16) & 15)*8);
    }
  __syncthreads();   // all waves done reading Q scratch (Vs region now free)

  f32x4 o[2][8];
  f32x4 z4 = {0.f,0.f,0.f,0.f};
  #pragma unroll
  for (int qs=0;qs<2;qs++) for (int dt=0;dt<8;dt++) o[qs][dt] = z4;
  float mrow[2] = {-1e30f, -1e30f};
  float lrow[2] = {0.f, 0.f};
  const float cs = 0.08838834764831845f * 1.4426950408889634f;  // (1/sqrt(128))*log2(e)

  for (int kt = 0; kt < 16; kt++){
    // issue V_kt gll now — overlaps QK + softmax; drained by mid-barrier
    #pragma unroll
    for (int j=0;j<8;j++){
      int d = j*16 + w*4 + (l >> 4);
      int g = (l & 15) ^ (d & 15);
      gll16(Vbase + (size_t)d*SEQ + kt*128 + g*8, Vs + j*2048 + w*512);
    }

    // S^T = K Q^T : lane q-col=c16, key rows quad*4+r (+16*kt8)
    f32x4 s[2][8];
    #pragma unroll
    for (int qs=0;qs<2;qs++) for (int kt8=0;kt8<8;kt8++) s[qs][kt8] = z4;
    #pragma unroll
    for (int kt8=0; kt8<8; kt8++){
      #pragma unroll
      for (int kk=0;kk<4;kk++){
        int ch = kk*4 + q;
        bf16x8 kf = *(const bf16x8*)(Ks + (kt8*16 + c16)*128 + ((ch ^ c16) & 15)*8);
        s[0][kt8] = __builtin_amdgcn_mfma_f32_16x16x32_bf16(kf, qf[0][kk], s[0][kt8], 0,0,0);
        s[1][kt8] = __builtin_amdgcn_mfma_f32_16x16x32_bf16(kf, qf[1][kk], s[1][kt8], 0,0,0);
      }
    }

    // online softmax: 32 in-lane values per q-set + 2 cross-quad shuffles
    float alpha[2];
    #pragma unroll
    for (int qs=0; qs<2; qs++){
      float vmax = s[qs][0][0];
      #pragma unroll
      for (int kt8=0;kt8<8;kt8++)
        #pragma unroll
        for (int r=0;r<4;r++) vmax = fmaxf(vmax, s[qs][kt8][r]);
      vmax = fmaxf(vmax, __shfl_xor(vmax, 16));
      vmax = fmaxf(vmax, __shfl_xor(vmax, 32));
      float mold = mrow[qs];
      float mnew = fmaxf(mold, vmax);
      float a = exp2f((mold - mnew)*cs);
      float mc = mnew*cs;
      float rsum = 0.f;
      #pragma unroll
      for (int kt8=0;kt8<8;kt8++)
        #pragma unroll
        for (int r=0;r<4;r++){
          float p = exp2f(__builtin_fmaf(s[qs][kt8][r], cs, -mc));
          s[qs][kt8][r] = p; rsum += p;
        }
      rsum += __shfl_xor(rsum, 16);
      rsum += __shfl_xor(rsum, 32);
      lrow[qs] = lrow[qs]*a + rsum;
      mrow[qs] = mnew;
      alpha[qs] = a;
    }
    // rescale O (skip when no lane's max moved — exact)
    unsigned long long allone = __ballot(alpha[0] == 1.f && alpha[1] == 1.f);
    if (allone != ~0ull){
      #pragma unroll
      for (int qs=0;qs<2;qs++)
        #pragma unroll
        for (int dt=0;dt<8;dt++)
          #pragma unroll
          for (int r=0;r<4;r++) o[qs][dt][r] *= alpha[qs];
    }

    // pack P to bf16 registers
    union { unsigned u[2]; bf16x4 v; } P[2][8];
    #pragma unroll
    for (int kt8=0;kt8<8;kt8++){
      P[0][kt8].u[0] = pack2bf(s[0][kt8][0], s[0][kt8][1]);
      P[0][kt8].u[1] = pack2bf(s[0][kt8][2], s[0][kt8][3]);
      P[1][kt8].u[0] = pack2bf(s[1][kt8][0], s[1][kt8][1]);
      P[1][kt8].u[1] = pack2bf(s[1][kt8][2], s[1][kt8][3]);
    }

    __syncthreads();   // mid: V_kt arrived; all QK reads of Ks done

    // issue K_{kt+1} gll now — overlaps PV; drained by end-barrier
    if (kt < 15){
      #pragma unroll
      for (int j=0;j<8;j++){
        int r = j*16 + w*4 + (l >> 4);
        int g = (l & 15) ^ (r & 15);
        gll16(Kbase + (size_t)((kt+1)*128 + r)*HD + g*8, Ks + j*2048 + w*512);
      }
    }

    // O^T += V^T P^T : A = V^T frag (LDS b64), B = P frag (registers)
    #pragma unroll
    for (int kt8=0; kt8<8; kt8++){
      int c4 = kt8*4 + q;
      #pragma unroll
      for (int dt=0; dt<8; dt++){
        int d = dt*16 + c16;
        int p8 = (c4 >> 1) ^ (d & 15);
        bf16x4 vf = *(const bf16x4*)(Vs + d*128 + p8*8 + (c4 & 1)*4);
        o[0][dt] = __builtin_amdgcn_mfma_f32_16x16x16bf16_1k(vf, P[0][kt8].v, o[0][dt], 0,0,0);
        o[1][dt] = __builtin_amdgcn_mfma_f32_16x16x16bf16_1k(vf, P[1][kt8].v, o[1][dt], 0,0,0);
      }
    }
    __syncthreads();   // end: K_{kt+1} arrived; all PV reads of Vs done
  }

  // normalize + write: lane holds O[q=c16+16qs][d=dt*16+quad*4+r] -> ushort4 along d
  #pragma unroll
  for (int qs=0;qs<2;qs++){
    float inv = 1.f / lrow[qs];
    int qrow = qt*128 + w*32 + qs*16 + c16;
    u16* dst = attnb + ((size_t)(b*SEQ) + qrow)*D_MODEL + h*HD + q*4;
    #pragma unroll
    for (int dt=0;dt<8;dt++){
      ushort4 pk;
      pk.x = f2bf(o[qs][dt][0]*inv);
      pk.y = f2bf(o[qs][dt][1]*inv);
      pk.z = f2bf(o[qs][dt][2]*inv);
      pk.w = f2bf(o[qs][dt][3]*inv);
      *(ushort4*)(dst + dt*16) = pk;
    }
  }
}

extern "C" void kernel_launch(void* const* d_in, const int* in_sizes, int n_in,
                              void* d_out, int out_size, void* d_ws, size_t ws_size,
                              hipStream_t stream) {
  (void)in_sizes; (void)n_in; (void)out_size; (void)ws_size;
  const float* query = (const float*)d_in[0];
  const float* key   = (const float*)d_in[1];
  const float* value = (const float*)d_in[2];
  const float* Wq    = (const float*)d_in[3];
  const float* bq    = (const float*)d_in[4];
  const float* Wk    = (const float*)d_in[5];
  const float* bk    = (const float*)d_in[6];
  const float* Wv    = (const float*)d_in[7];
  const float* bv    = (const float*)d_in[8];
  const float* Wo    = (const float*)d_in[9];
  const float* bo    = (const float*)d_in[10];
  float* out = (float*)d_out;

  char* W = (char*)d_ws;
  u16*  qb     = (u16*) (W + 0);          // 16 MB  bf16 query [4096][2048]
  u16*  kb     = (u16*) (W + 16777216);   // 16 MB  bf16 key
  u16*  vb     = (u16*) (W + 33554432);   // 16 MB  bf16 value
  u16*  WqT    = (u16*) (W + 50331648);   //  8 MB  Wq^T  [2048][2048]
  u16*  WoT    = (u16*) (W + 58720256);   //  8 MB  Wo^T
  u16*  WkT    = (u16*) (W + 67108864);   // .5 MB  Wk^T  [128][2048]
  u16*  WvT    = (u16*) (W + 67633152);   // .5 MB  Wv^T
  u16*  Qp     = (u16*) (W + 68157440);   // 16 MB  Q proj bf16 [4096][2048]
  u16*  Kp     = (u16*) (W + 84934656);   //  1 MB  K proj bf16 [4096][128]
  u16*  VpT    = (u16*) (W + 85983232);   //  1 MB  V proj^T bf16 [B][128][2048]
  u16*  attnb  = (u16*) (W + 87031808);   // 16 MB  attention out bf16 [4096][2048]
  float* kvpart= (float*)(W + 103809024); // 16 MB  split-K partials [4][2][4096][128]

  convert3_kernel<<<8192, 256, 0, stream>>>(
      (const float4*)query, (const float4*)key, (const float4*)value,
      (ushort4*)qb, (ushort4*)kb, (ushort4*)vb);
  transpose_all<<<8704, 256, 0, stream>>>(Wq, Wo, Wk, Wv, WqT, WoT, WkT, WvT);
  proj_kernel<<<768, 256, 0, stream>>>(qb, kb, vb, WqT, WkT, WvT, bq, Qp, kvpart);
  kv_reduce_kernel<<<2048, 256, 0, stream>>>(kvpart, bk, bv, Kp, VpT);
  attn_kernel<<<dim3(16,32), 256, 0, stream>>>(Qp, Kp, VpT, attnb);
  oproj_kernel<<<dim3(32,16), 256, 0, stream>>>(attnb, WoT, bo, out);
}